// Round 3
// baseline (214.167 us; speedup 1.0000x reference)
//
#include <hip/hip_runtime.h>

// Q = L @ L^T for 3x3 lower-triangular L packed as 6 floats per item:
// packed (row,col) = (0,0),(1,0),(1,1),(2,0),(2,1),(2,2) -> a,b,c,d,e,f
// Uniques: u0=a*a u1=a*b u2=a*d u3=b*b+c*c u4=b*d+c*e u5=d*d+e*e+f*f
// Row-major out[0..8] = [u0,u1,u2, u1,u3,u4, u2,u4,u5]
//
// R6 = R5 resubmitted (R5 bench died on container infra, no measurement).
// R5: drop s_in entirely. Thread's two items (tid, tid+256) are 6 contiguous
// floats each, contiguous across the wave (24B/lane, 1536B/wave) -> direct
// global->reg loads are fully coalesced (3x dwordx2). Gains vs R4:
//   - one barrier per block instead of two
//   - LDS 30KB -> 18KB: 8 blocks/CU = 32 waves/CU (max) vs 5 blocks
//   - no stride-6 LDS read conflicts, -24KB/block LDS traffic
// s_out staging kept: it is what makes the 9-floats/item stores coalesced
// (contiguous f4 lanes). Stride-9 word writes to s_out are 2-way = free.
// Decisive experiment: if dur_us stays ~211-214, kernel is at the ~40us BW
// floor (251.7MB @ ~6.5TB/s) and dur_us is dominated by harness reset
// (~92us fill + ~31us restore + small-dispatch overhead) -> roofline.

#define THREADS 256
#define IPB 512  // items per block: s_out 18 KB

typedef float f4 __attribute__((ext_vector_type(4)));
typedef float f2 __attribute__((ext_vector_type(2)));

__global__ __launch_bounds__(THREADS) void chol_to_cov_kernel(
    const float* __restrict__ in, float* __restrict__ out, long long n_items) {
  __shared__ __attribute__((aligned(16))) float s_out[IPB * 9];  // 18 KB

  const int tid = threadIdx.x;
  const long long block_base = (long long)blockIdx.x * IPB;

  if (block_base + IPB <= n_items) {
    // ---- compute: direct global->reg loads, static LDS stores ----
#pragma unroll
    for (int t = 0; t < 2; t++) {
      const int item = tid + t * THREADS;  // < 512
      const f2* __restrict__ p =
          (const f2*)(in + (block_base + item) * 6);  // 8B aligned
      const f2 x = __builtin_nontemporal_load(&p[0]);
      const f2 y = __builtin_nontemporal_load(&p[1]);
      const f2 z = __builtin_nontemporal_load(&p[2]);
      const float a = x[0], b = x[1], c = y[0];
      const float d = y[1], e0 = z[0], f = z[1];
      const float u1 = a * b;
      const float u2 = a * d;
      const float u4 = b * d + c * e0;
      float* q = s_out + item * 9;  // stride-9 words: 2 lanes/bank = free
      q[0] = a * a;
      q[1] = u1;
      q[2] = u2;
      q[3] = u1;
      q[4] = b * b + c * c;
      q[5] = u4;
      q[6] = u2;
      q[7] = u4;
      q[8] = d * d + e0 * e0 + f * f;
    }
    __syncthreads();

    // ---- LDS -> global, contiguous float4 lanes, nontemporal ----
    f4* __restrict__ out4 = (f4*)(out + block_base * 9);
    const f4* s4o = (const f4*)s_out;
#pragma unroll
    for (int k = 0; k < 4; k++) {
      const int idx = tid + k * THREADS;  // < 1024
      __builtin_nontemporal_store(s4o[idx], &out4[idx]);
    }
    const int idx4 = tid + 4 * THREADS;  // remaining 128 float4
    if (idx4 < (IPB * 9) / 4) {          // wave-uniform (waves 0-1 only)
      __builtin_nontemporal_store(s4o[idx4], &out4[idx4]);
    }
  } else {
    // ---- guarded tail path (unused at 4096*1024 items) ----
    for (long long it = block_base + tid; it < n_items; it += THREADS) {
      const float a = in[it * 6 + 0];
      const float b = in[it * 6 + 1];
      const float c = in[it * 6 + 2];
      const float d = in[it * 6 + 3];
      const float e = in[it * 6 + 4];
      const float f = in[it * 6 + 5];
      float* o = out + it * 9;
      o[0] = a * a;
      o[1] = a * b;
      o[2] = a * d;
      o[3] = a * b;
      o[4] = b * b + c * c;
      o[5] = b * d + c * e;
      o[6] = a * d;
      o[7] = b * d + c * e;
      o[8] = d * d + e * e + f * f;
    }
  }
}

extern "C" void kernel_launch(void* const* d_in, const int* in_sizes, int n_in,
                              void* d_out, int out_size, void* d_ws,
                              size_t ws_size, hipStream_t stream) {
  const float* in = (const float*)d_in[0];
  float* out = (float*)d_out;
  const long long n_items = (long long)in_sizes[0] / 6;  // 4,194,304
  const long long grid = (n_items + IPB - 1) / IPB;      // 8192
  chol_to_cov_kernel<<<(int)grid, THREADS, 0, stream>>>(in, out, n_items);
}